// Round 10
// baseline (278.333 us; speedup 1.0000x reference)
//
#include <hip/hip_runtime.h>
#include <hip/hip_fp16.h>

// Problem constants (from reference file)
#define N_NODES 100000
#define F_DIM   32
#define D_DIM   3
#define O_DIM   32
#define E_EDGES 1600000

#define CAP        32          // bucket slots per node (Poisson(16): P(>32)~1e-4)
#define SPILL_MAX  262144      // spill capacity (edges beyond CAP)
#define NSTRIPES   512         // edge stripes; grid = 8 * NSTRIPES blocks
#define EPS        (E_EDGES / NSTRIPES)   // 3125 edges per stripe

// 8-byte record (validated: absmax 0.0156 < 0.106):
//   lo = col(17b) | q0<<17 (15b, scale 32768, rounded)
//   hi = q1(16b) | q2<<16 (16b, scale 65536, rounded)

// 16-byte spill record: row, col, q0|q1<<16, q2 (16-bit quantization)
struct __align__(16) Spill { unsigned row, col, q01, q2; };

// ---------------------------------------------------------------------------
// Bucket scatter, XCD-sliced for L2 write locality (validated round 6).
// ROUND 10: fp32->fp16 conversion restricted to blocks 0..511 so the other
// 3584 blocks start scattering immediately (round 9 ran it in all blocks,
// serializing every block's start: bucket 65 -> ~80 us).
// ---------------------------------------------------------------------------
__global__ __launch_bounds__(256) void k_bucket(
        const int* __restrict__ ei, const float* __restrict__ pseudo,
        const float* __restrict__ x, __half* __restrict__ xh,
        int* __restrict__ cnt, int* __restrict__ spillcnt,
        unsigned long long* __restrict__ rec, Spill* __restrict__ spill) {
    // ---- preamble (512 blocks only): x (fp32) -> xh (fp16), vectorized ----
    if (blockIdx.x < 512) {
        const int t  = blockIdx.x * 256 + threadIdx.x;
        const int NQ = N_NODES * F_DIM / 4;            // 800,000 quads
        for (int i = t; i < NQ; i += 512 * 256) {
            const float4 v = ((const float4*)x)[i];
            ushort4 h;
            h.x = __half_as_ushort(__float2half_rn(v.x));
            h.y = __half_as_ushort(__float2half_rn(v.y));
            h.z = __half_as_ushort(__float2half_rn(v.z));
            h.w = __half_as_ushort(__float2half_rn(v.w));
            ((ushort4*)xh)[i] = h;
        }
    }

    // ---- bucket scatter: slice c=b&7 takes rows with ((row>>12)&7)==c ----
    const int c    = blockIdx.x & 7;
    const int s    = blockIdx.x >> 3;
    const int base = s * EPS;
    const int end  = base + EPS;

    for (int e = base + threadIdx.x; e < end; e += 256) {
        const int row = ei[e];
        if (((row >> 12) & 7) != c) continue;
        const int   col = ei[E_EDGES + e];
        const float p0  = pseudo[e * 3 + 0];
        const float p1  = pseudo[e * 3 + 1];
        const float p2  = pseudo[e * 3 + 2];
        const int p = atomicAdd(&cnt[row], 1);
        if (p < CAP) {
            const unsigned q0 = min((unsigned)(p0 * 32768.f + 0.5f), 32767u);
            const unsigned q1 = min((unsigned)(p1 * 65536.f + 0.5f), 65535u);
            const unsigned q2 = min((unsigned)(p2 * 65536.f + 0.5f), 65535u);
            const unsigned lo = (unsigned)col | (q0 << 17);
            const unsigned hi = q1 | (q2 << 16);
            rec[(size_t)row * CAP + p] = ((unsigned long long)hi << 32) | lo;
        } else {
            const int t = atomicAdd(spillcnt, 1);
            if (t < SPILL_MAX) {
                Spill sp;
                sp.row = (unsigned)row;
                sp.col = (unsigned)col;
                sp.q01 = min((unsigned)(p0 * 65536.f + 0.5f), 65535u)
                       | (min((unsigned)(p1 * 65536.f + 0.5f), 65535u) << 16);
                sp.q2  = min((unsigned)(p2 * 65536.f + 0.5f), 65535u);
                spill[t] = sp;
            }
        }
    }
}

// ---------------------------------------------------------------------------
// One wave per node, round-9 4-chain loop (gather 105 -> 98 us).
// ROUND 10: XCD-ALIGNED node mapping. Block B (slice c=B&7, on XCD~c by the
// same blockIdx%8 heuristic validated in round 6) processes exactly the
// nodes whose buckets slice c wrote: (n>>12)&7 == c. Per-XCD rec slice is
// 3.2 MB < 4 MB L2, so rec reads become own-XCD L2 hits instead of HBM
// refetches (round 9: rec ~25.6 MB of the 62 MB FETCH, cross-XCD).
// Mapping: k = 2*(B>>3)+wid; n = (c + 8*(k>>12))*4096 + (k&4095); n<N guard.
// Epilogue uses wave-private LDS with no barrier (validated in round 5's
// fused kernel) so out-of-range waves can simply return.
// ---------------------------------------------------------------------------
__global__ __launch_bounds__(128) void k_gather_linear(
        const __half* __restrict__ xh, const float* __restrict__ x,
        const int* __restrict__ cnt,
        const unsigned long long* __restrict__ rec,
        const int* __restrict__ spillcnt, const Spill* __restrict__ spill,
        const float* __restrict__ mu, const float* __restrict__ sigma,
        const float* __restrict__ W, const float* __restrict__ b,
        float* __restrict__ out) {
    __shared__ float arow[2][F_DIM];

    const int lane = threadIdx.x & 63;
    const int wid  = threadIdx.x >> 6;
    const int f    = lane & 31;
    const int half = lane >> 5;

    // XCD-aligned node id
    const int c = blockIdx.x & 7;
    const int k = 2 * (blockIdx.x >> 3) + wid;
    const int n = ((c + 8 * (k >> 12)) << 12) + (k & 4095);
    if (n >= N_NODES) return;                // whole-wave uniform exit

    const float m0 = mu[f * 3 + 0], m1 = mu[f * 3 + 1], m2 = mu[f * 3 + 2];
    const float s0 = sigma[f * 3 + 0], s1 = sigma[f * 3 + 1], s2 = sigma[f * 3 + 2];
    const float c0 = 0.5f / (1e-14f + s0 * s0);
    const float c1 = 0.5f / (1e-14f + s1 * s1);
    const float c2 = 0.5f / (1e-14f + s2 * s2);

    const int cn = cnt[n];
    const int m  = min(cn, CAP);
    const unsigned long long* rb = rec + (size_t)n * CAP;

    float a0 = 0.f, a1 = 0.f, a2 = 0.f, a3 = 0.f;
    int j = half;

    // main loop: 4 records per half per iteration (8 per wave)
    for (; j + 6 < m; j += 8) {
        const unsigned long long r0 = rb[j];
        const unsigned long long r1 = rb[j + 2];
        const unsigned long long r2 = rb[j + 4];
        const unsigned long long r3 = rb[j + 6];
        const __half xv0 = xh[(size_t)((unsigned)r0 & 0x1FFFFu) * F_DIM + f];
        const __half xv1 = xh[(size_t)((unsigned)r1 & 0x1FFFFu) * F_DIM + f];
        const __half xv2 = xh[(size_t)((unsigned)r2 & 0x1FFFFu) * F_DIM + f];
        const __half xv3 = xh[(size_t)((unsigned)r3 & 0x1FFFFu) * F_DIM + f];
        const unsigned lo0 = (unsigned)r0, hi0 = (unsigned)(r0 >> 32);
        const unsigned lo1 = (unsigned)r1, hi1 = (unsigned)(r1 >> 32);
        const unsigned lo2 = (unsigned)r2, hi2 = (unsigned)(r2 >> 32);
        const unsigned lo3 = (unsigned)r3, hi3 = (unsigned)(r3 >> 32);
        const float d00 = (float)(lo0 >> 17) * (1.f / 32768.f) - m0;
        const float d01 = (float)(hi0 & 0xFFFFu) * (1.f / 65536.f) - m1;
        const float d02 = (float)(hi0 >> 16) * (1.f / 65536.f) - m2;
        const float d10 = (float)(lo1 >> 17) * (1.f / 32768.f) - m0;
        const float d11 = (float)(hi1 & 0xFFFFu) * (1.f / 65536.f) - m1;
        const float d12 = (float)(hi1 >> 16) * (1.f / 65536.f) - m2;
        const float d20 = (float)(lo2 >> 17) * (1.f / 32768.f) - m0;
        const float d21 = (float)(hi2 & 0xFFFFu) * (1.f / 65536.f) - m1;
        const float d22 = (float)(hi2 >> 16) * (1.f / 65536.f) - m2;
        const float d30 = (float)(lo3 >> 17) * (1.f / 32768.f) - m0;
        const float d31 = (float)(hi3 & 0xFFFFu) * (1.f / 65536.f) - m1;
        const float d32 = (float)(hi3 >> 16) * (1.f / 65536.f) - m2;
        const float g0 = __expf(-(c0 * d00 * d00 + c1 * d01 * d01 + c2 * d02 * d02));
        const float g1 = __expf(-(c0 * d10 * d10 + c1 * d11 * d11 + c2 * d12 * d12));
        const float g2 = __expf(-(c0 * d20 * d20 + c1 * d21 * d21 + c2 * d22 * d22));
        const float g3 = __expf(-(c0 * d30 * d30 + c1 * d31 * d31 + c2 * d32 * d32));
        a0 += __half2float(xv0) * g0;
        a1 += __half2float(xv1) * g1;
        a2 += __half2float(xv2) * g2;
        a3 += __half2float(xv3) * g3;
    }
    // tail: 0..3 records per half
    for (; j < m; j += 2) {
        const unsigned long long r0 = rb[j];
        const __half xv0 = xh[(size_t)((unsigned)r0 & 0x1FFFFu) * F_DIM + f];
        const unsigned lo0 = (unsigned)r0, hi0 = (unsigned)(r0 >> 32);
        const float d00 = (float)(lo0 >> 17) * (1.f / 32768.f) - m0;
        const float d01 = (float)(hi0 & 0xFFFFu) * (1.f / 65536.f) - m1;
        const float d02 = (float)(hi0 >> 16) * (1.f / 65536.f) - m2;
        const float g0 = __expf(-(c0 * d00 * d00 + c1 * d01 * d01 + c2 * d02 * d02));
        a0 += __half2float(xv0) * g0;
    }

    // rare overflow: scan the tiny spill list (half 0 only; fp32 x — exact)
    if (cn > CAP && half == 0) {
        const int sn = min(*spillcnt, SPILL_MAX);
        for (int kk = 0; kk < sn; ++kk) {
            const Spill sp = spill[kk];      // broadcast, L2-hot
            if ((int)sp.row != n) continue;
            const float d0 = (float)(sp.q01 & 0xFFFFu) * (1.f / 65536.f) - m0;
            const float d1 = (float)(sp.q01 >> 16) * (1.f / 65536.f) - m1;
            const float d2 = (float)sp.q2 * (1.f / 65536.f) - m2;
            const float g  = __expf(-(c0 * d0 * d0 + c1 * d1 * d1 + c2 * d2 * d2));
            a0 += x[(size_t)sp.col * F_DIM + f] * g;
        }
    }

    float a = (a0 + a1) + (a2 + a3);
    a += __shfl_xor(a, 32, 64);              // combine halves
    if (half == 0) arow[wid][f] = a;
    // wave-private LDS row: in-wave DS ordering (validated round 5, no barrier)

    // Linear epilogue: lane computes out[n][o], o=f; halves split the f-sum.
    float w[16];
    const float* wrow = W + (size_t)f * F_DIM + half * 16;   // W[o][16h..]
#pragma unroll
    for (int q = 0; q < 4; ++q) {
        const float4 t = ((const float4*)wrow)[q];
        w[4 * q + 0] = t.x; w[4 * q + 1] = t.y;
        w[4 * q + 2] = t.z; w[4 * q + 3] = t.w;
    }
    const float* ar = &arow[wid][half * 16];
    float s = 0.f;
#pragma unroll
    for (int q = 0; q < 4; ++q) {
        const float4 v = ((const float4*)ar)[q];  // broadcast b128 read
        s += v.x * w[4 * q + 0] + v.y * w[4 * q + 1]
           + v.z * w[4 * q + 2] + v.w * w[4 * q + 3];
    }
    s += __shfl_xor(s, 32, 64);
    if (half == 0) out[(size_t)n * F_DIM + f] = s + b[f];
}

// ---------------------------------------------------------------------------
// Fallback (ws too small): round-1 atomic path, proven correct.
// ---------------------------------------------------------------------------
__global__ void gmm_edge_scatter(const float* __restrict__ x,
                                 const int*   __restrict__ edge_index,
                                 const float* __restrict__ pseudo,
                                 const float* __restrict__ mu,
                                 const float* __restrict__ sigma,
                                 float* __restrict__ acc) {
    const int f = threadIdx.x & 31;
    const float m0 = mu[f * 3 + 0], m1 = mu[f * 3 + 1], m2 = mu[f * 3 + 2];
    const float s0 = sigma[f * 3 + 0], s1 = sigma[f * 3 + 1], s2 = sigma[f * 3 + 2];
    const float c0 = 0.5f / (1e-14f + s0 * s0);
    const float c1 = 0.5f / (1e-14f + s1 * s1);
    const float c2 = 0.5f / (1e-14f + s2 * s2);
    int group   = (blockIdx.x * blockDim.x + threadIdx.x) >> 5;
    int ngroups = (gridDim.x * blockDim.x) >> 5;
    for (int e = group; e < E_EDGES; e += ngroups) {
        const int row = edge_index[e];
        const int col = edge_index[E_EDGES + e];
        const float p0 = pseudo[e * 3 + 0], p1 = pseudo[e * 3 + 1], p2 = pseudo[e * 3 + 2];
        const float d0 = p0 - m0, d1 = p1 - m1, d2 = p2 - m2;
        const float g  = __expf(-(c0 * d0 * d0 + c1 * d1 * d1 + c2 * d2 * d2));
        atomicAdd(&acc[(size_t)row * F_DIM + f], x[(size_t)col * F_DIM + f] * g);
    }
}

__global__ void gmm_linear2(const float* __restrict__ acc,
                            const float* __restrict__ W,
                            const float* __restrict__ b,
                            float* __restrict__ out) {
    const int o = threadIdx.x & 31;
    const int n = (blockIdx.x * blockDim.x + threadIdx.x) >> 5;
    if (n >= N_NODES) return;
    const float* wrow = W + (size_t)o * F_DIM;
    const float* ap   = acc + (size_t)n * F_DIM;
    float s = b[o];
#pragma unroll
    for (int q = 0; q < 8; ++q) {
        const float4 wv = ((const float4*)wrow)[q];
        const float4 av = ((const float4*)ap)[q];
        s += av.x * wv.x + av.y * wv.y + av.z * wv.z + av.w * wv.w;
    }
    out[(size_t)n * F_DIM + o] = s;
}

extern "C" void kernel_launch(void* const* d_in, const int* in_sizes, int n_in,
                              void* d_out, int out_size, void* d_ws, size_t ws_size,
                              hipStream_t stream) {
    const float* x          = (const float*)d_in[0];
    const int*   edge_index = (const int*)  d_in[1];
    const float* pseudo     = (const float*)d_in[2];
    const float* mu         = (const float*)d_in[3];
    const float* sigma      = (const float*)d_in[4];
    const float* W          = (const float*)d_in[5];
    const float* b          = (const float*)d_in[6];
    float*       out        = (float*)d_out;

    // Workspace layout
    const size_t CNT_OFF    = 0;                                  // N ints
    const size_t SPC_OFF    = (size_t)N_NODES * 4;                // 1 int
    const size_t ZERO_BYTES = SPC_OFF + 4;                        // memset range
    const size_t REC_OFF    = 409600;                             // 4K-aligned
    const size_t REC_BYTES  = (size_t)N_NODES * CAP * 8;          // 25.6 MB
    const size_t SPILL_OFF  = REC_OFF + REC_BYTES;                // 26,009,600
    const size_t XH_OFF     = SPILL_OFF + (size_t)SPILL_MAX * 16; // 30,203,904
    const size_t NEED       = XH_OFF + (size_t)N_NODES * F_DIM * 2; // ~36.6 MB

    if (ws_size >= NEED) {
        char* ws = (char*)d_ws;
        int*                cnt      = (int*)(ws + CNT_OFF);
        int*                spillcnt = (int*)(ws + SPC_OFF);
        unsigned long long* rec      = (unsigned long long*)(ws + REC_OFF);
        Spill*              spill    = (Spill*)(ws + SPILL_OFF);
        __half*             xh       = (__half*)(ws + XH_OFF);

        hipMemsetAsync(ws, 0, ZERO_BYTES, stream);    // cnt + spillcnt only
        k_bucket<<<8 * NSTRIPES, 256, 0, stream>>>(
            edge_index, pseudo, x, xh, cnt, spillcnt, rec, spill);
        // 8 slices x 7000 block-slots: covers slice 0's 13984 nodes; blocks
        // whose mapped n >= N exit immediately.
        k_gather_linear<<<8 * 7000, 128, 0, stream>>>(
            xh, x, cnt, rec, spillcnt, spill, mu, sigma, W, b, out);
    } else {
        float* acc = (float*)d_ws;
        hipMemsetAsync(acc, 0, (size_t)N_NODES * F_DIM * sizeof(float), stream);
        gmm_edge_scatter<<<4096, 256, 0, stream>>>(x, edge_index, pseudo, mu, sigma, acc);
        gmm_linear2<<<(N_NODES * 32 + 255) / 256, 256, 0, stream>>>(acc, W, b, out);
    }
}

// Round 11
// 262.464 us; speedup vs baseline: 1.0605x; 1.0605x over previous
//
#include <hip/hip_runtime.h>

// Problem constants (from reference file)
#define N_NODES 100000
#define F_DIM   32
#define D_DIM   3
#define O_DIM   32
#define E_EDGES 1600000

#define CAP        32          // bucket slots per node (Poisson(16): P(>32)~1e-4)
#define SPILL_MAX  262144      // spill capacity (edges beyond CAP)
#define NSTRIPES   512         // edge stripes; grid = 8 * NSTRIPES blocks
#define EPS        (E_EDGES / NSTRIPES)   // 3125 edges per stripe

// 8-byte record (validated: absmax 0.0156 < 0.106):
//   lo = col(17b) | q0<<17 (15b, scale 32768, rounded)
//   hi = q1(16b) | q2<<16 (16b, scale 65536, rounded)

// 16-byte spill record: row, col, q0|q1<<16, q2 (16-bit quantization)
struct __align__(16) Spill { unsigned row, col, q01, q2; };

// ---------------------------------------------------------------------------
// Bucket scatter, XCD-sliced for L2 write locality — EXACT round-6 version
// (bucket ~66 us; rounds 9/10 showed the fp16-x preamble costs +15 us here
// for only -7 us in the gather: reverted).
// ---------------------------------------------------------------------------
__global__ __launch_bounds__(256) void k_bucket(
        const int* __restrict__ ei, const float* __restrict__ pseudo,
        int* __restrict__ cnt, int* __restrict__ spillcnt,
        unsigned long long* __restrict__ rec, Spill* __restrict__ spill) {
    const int c    = blockIdx.x & 7;
    const int s    = blockIdx.x >> 3;
    const int base = s * EPS;
    const int end  = base + EPS;

    for (int e = base + threadIdx.x; e < end; e += 256) {
        const int row = ei[e];
        if (((row >> 12) & 7) != c) continue;
        const int   col = ei[E_EDGES + e];
        const float p0  = pseudo[e * 3 + 0];
        const float p1  = pseudo[e * 3 + 1];
        const float p2  = pseudo[e * 3 + 2];
        const int p = atomicAdd(&cnt[row], 1);
        if (p < CAP) {
            const unsigned q0 = min((unsigned)(p0 * 32768.f + 0.5f), 32767u);
            const unsigned q1 = min((unsigned)(p1 * 65536.f + 0.5f), 65535u);
            const unsigned q2 = min((unsigned)(p2 * 65536.f + 0.5f), 65535u);
            const unsigned lo = (unsigned)col | (q0 << 17);
            const unsigned hi = q1 | (q2 << 16);
            rec[(size_t)row * CAP + p] = ((unsigned long long)hi << 32) | lo;
        } else {
            const int t = atomicAdd(spillcnt, 1);
            if (t < SPILL_MAX) {
                Spill sp;
                sp.row = (unsigned)row;
                sp.col = (unsigned)col;
                sp.q01 = min((unsigned)(p0 * 65536.f + 0.5f), 65535u)
                       | (min((unsigned)(p1 * 65536.f + 0.5f), 65535u) << 16);
                sp.q2  = min((unsigned)(p2 * 65536.f + 0.5f), 65535u);
                spill[t] = sp;
            }
        }
    }
}

// ---------------------------------------------------------------------------
// One wave per node. ROUND 11: CHANNEL-PAIRING. Lane handles channels
// (2*fq, 2*fq+1), fq = lane&15; the wave's 4 16-lane groups (q = lane>>4)
// split the bucket with stride 4. Wins vs round-6 half-split:
//   - record unpack + address math serve 2 channels (per-channel VALU ~halved)
//   - x loads are float2 (same bytes, half the instructions)
//   - 4 groups x 2 chains = 2x independent load chains per wave (latency)
// 256-thread blocks (4 waves) for occupancy; wave-private LDS row, no barrier
// (validated rounds 5/10). Cross-group combine: shfl_xor 16 then 32.
// ---------------------------------------------------------------------------
__global__ __launch_bounds__(256) void k_gather_linear(
        const float* __restrict__ x, const int* __restrict__ cnt,
        const unsigned long long* __restrict__ rec,
        const int* __restrict__ spillcnt, const Spill* __restrict__ spill,
        const float* __restrict__ mu, const float* __restrict__ sigma,
        const float* __restrict__ W, const float* __restrict__ b,
        float* __restrict__ out) {
    __shared__ float arow[4][F_DIM];

    const int lane = threadIdx.x & 63;
    const int wid  = threadIdx.x >> 6;            // wave in block: 0..3
    const int fq   = lane & 15;                   // channel pair index
    const int q    = lane >> 4;                   // edge group: 0..3
    const int f0   = 2 * fq;                      // channels f0, f0+1
    const int n    = blockIdx.x * 4 + wid;        // grid exact: n < N_NODES

    // per-channel-pair constants
    const float ma0 = mu[f0 * 3 + 0], ma1 = mu[f0 * 3 + 1], ma2 = mu[f0 * 3 + 2];
    const float mb0 = mu[f0 * 3 + 3], mb1 = mu[f0 * 3 + 4], mb2 = mu[f0 * 3 + 5];
    const float sa0 = sigma[f0 * 3 + 0], sa1 = sigma[f0 * 3 + 1], sa2 = sigma[f0 * 3 + 2];
    const float sb0 = sigma[f0 * 3 + 3], sb1 = sigma[f0 * 3 + 4], sb2 = sigma[f0 * 3 + 5];
    const float ca0 = 0.5f / (1e-14f + sa0 * sa0);
    const float ca1 = 0.5f / (1e-14f + sa1 * sa1);
    const float ca2 = 0.5f / (1e-14f + sa2 * sa2);
    const float cb0 = 0.5f / (1e-14f + sb0 * sb0);
    const float cb1 = 0.5f / (1e-14f + sb1 * sb1);
    const float cb2 = 0.5f / (1e-14f + sb2 * sb2);

    const int cn = cnt[n];
    const int m  = min(cn, CAP);
    const unsigned long long* rb = rec + (size_t)n * CAP;
    const float2* x2 = (const float2*)x;

    float Ax0 = 0.f, Ay0 = 0.f, Ax1 = 0.f, Ay1 = 0.f;
    int j = q;

    // main loop: 2 records per group per iteration (8 per wave, 16 loads in flight)
    for (; j + 4 < m; j += 8) {
        const unsigned long long r0 = rb[j];
        const unsigned long long r1 = rb[j + 4];
        const unsigned lo0 = (unsigned)r0, hi0 = (unsigned)(r0 >> 32);
        const unsigned lo1 = (unsigned)r1, hi1 = (unsigned)(r1 >> 32);
        const float2 xv0 = x2[(size_t)(lo0 & 0x1FFFFu) * 16 + fq];
        const float2 xv1 = x2[(size_t)(lo1 & 0x1FFFFu) * 16 + fq];
        // shared unpack (serves both channels)
        const float u00 = (float)(lo0 >> 17) * (1.f / 32768.f);
        const float u01 = (float)(hi0 & 0xFFFFu) * (1.f / 65536.f);
        const float u02 = (float)(hi0 >> 16) * (1.f / 65536.f);
        const float u10 = (float)(lo1 >> 17) * (1.f / 32768.f);
        const float u11 = (float)(hi1 & 0xFFFFu) * (1.f / 65536.f);
        const float u12 = (float)(hi1 >> 16) * (1.f / 65536.f);
        // rec 0, channel a/b
        const float e0a0 = u00 - ma0, e0a1 = u01 - ma1, e0a2 = u02 - ma2;
        const float e0b0 = u00 - mb0, e0b1 = u01 - mb1, e0b2 = u02 - mb2;
        const float g0a = __expf(-(ca0 * e0a0 * e0a0 + ca1 * e0a1 * e0a1 + ca2 * e0a2 * e0a2));
        const float g0b = __expf(-(cb0 * e0b0 * e0b0 + cb1 * e0b1 * e0b1 + cb2 * e0b2 * e0b2));
        // rec 1, channel a/b
        const float e1a0 = u10 - ma0, e1a1 = u11 - ma1, e1a2 = u12 - ma2;
        const float e1b0 = u10 - mb0, e1b1 = u11 - mb1, e1b2 = u12 - mb2;
        const float g1a = __expf(-(ca0 * e1a0 * e1a0 + ca1 * e1a1 * e1a1 + ca2 * e1a2 * e1a2));
        const float g1b = __expf(-(cb0 * e1b0 * e1b0 + cb1 * e1b1 * e1b1 + cb2 * e1b2 * e1b2));
        Ax0 += xv0.x * g0a;  Ay0 += xv0.y * g0b;
        Ax1 += xv1.x * g1a;  Ay1 += xv1.y * g1b;
    }
    // tail: 0..1 record per group
    for (; j < m; j += 4) {
        const unsigned long long r0 = rb[j];
        const unsigned lo0 = (unsigned)r0, hi0 = (unsigned)(r0 >> 32);
        const float2 xv0 = x2[(size_t)(lo0 & 0x1FFFFu) * 16 + fq];
        const float u00 = (float)(lo0 >> 17) * (1.f / 32768.f);
        const float u01 = (float)(hi0 & 0xFFFFu) * (1.f / 65536.f);
        const float u02 = (float)(hi0 >> 16) * (1.f / 65536.f);
        const float e0a0 = u00 - ma0, e0a1 = u01 - ma1, e0a2 = u02 - ma2;
        const float e0b0 = u00 - mb0, e0b1 = u01 - mb1, e0b2 = u02 - mb2;
        const float g0a = __expf(-(ca0 * e0a0 * e0a0 + ca1 * e0a1 * e0a1 + ca2 * e0a2 * e0a2));
        const float g0b = __expf(-(cb0 * e0b0 * e0b0 + cb1 * e0b1 * e0b1 + cb2 * e0b2 * e0b2));
        Ax0 += xv0.x * g0a;  Ay0 += xv0.y * g0b;
    }

    // rare overflow: group 0 only (no double count), fp32 x — exact
    if (cn > CAP && q == 0) {
        const int sn = min(*spillcnt, SPILL_MAX);
        for (int k = 0; k < sn; ++k) {
            const Spill sp = spill[k];        // broadcast, L2-hot
            if ((int)sp.row != n) continue;
            const float u0 = (float)(sp.q01 & 0xFFFFu) * (1.f / 65536.f);
            const float u1 = (float)(sp.q01 >> 16) * (1.f / 65536.f);
            const float u2 = (float)sp.q2 * (1.f / 65536.f);
            const float da0 = u0 - ma0, da1 = u1 - ma1, da2 = u2 - ma2;
            const float db0 = u0 - mb0, db1 = u1 - mb1, db2 = u2 - mb2;
            const float ga = __expf(-(ca0 * da0 * da0 + ca1 * da1 * da1 + ca2 * da2 * da2));
            const float gb = __expf(-(cb0 * db0 * db0 + cb1 * db1 * db1 + cb2 * db2 * db2));
            const float2 xv = x2[(size_t)sp.col * 16 + fq];
            Ax0 += xv.x * ga;  Ay0 += xv.y * gb;
        }
    }

    // combine the 4 edge groups (lanes with equal fq): xor over bits 4, 5
    float ax = Ax0 + Ax1, ay = Ay0 + Ay1;
    ax += __shfl_xor(ax, 16, 64);  ay += __shfl_xor(ay, 16, 64);
    ax += __shfl_xor(ax, 32, 64);  ay += __shfl_xor(ay, 32, 64);
    if (q == 0) { arow[wid][f0] = ax; arow[wid][f0 + 1] = ay; }
    // wave-private LDS row: in-wave DS ordering, no barrier (rounds 5/10)

    // Linear epilogue (validated since round 4): lane o = lane&31, halves
    // split the 32-term f-sum (16 each), one shfl_xor(32) combines.
    const int o    = lane & 31;
    const int half = lane >> 5;
    float w[16];
    const float* wrow = W + (size_t)o * F_DIM + half * 16;   // W[o][16h..]
#pragma unroll
    for (int t = 0; t < 4; ++t) {
        const float4 v = ((const float4*)wrow)[t];
        w[4 * t + 0] = v.x; w[4 * t + 1] = v.y;
        w[4 * t + 2] = v.z; w[4 * t + 3] = v.w;
    }
    const float* ar = &arow[wid][half * 16];
    float s = 0.f;
#pragma unroll
    for (int t = 0; t < 4; ++t) {
        const float4 v = ((const float4*)ar)[t];  // broadcast b128 read
        s += v.x * w[4 * t + 0] + v.y * w[4 * t + 1]
           + v.z * w[4 * t + 2] + v.w * w[4 * t + 3];
    }
    s += __shfl_xor(s, 32, 64);
    if (half == 0) out[(size_t)n * F_DIM + o] = s + b[o];
}

// ---------------------------------------------------------------------------
// Fallback (ws too small): round-1 atomic path, proven correct.
// ---------------------------------------------------------------------------
__global__ void gmm_edge_scatter(const float* __restrict__ x,
                                 const int*   __restrict__ edge_index,
                                 const float* __restrict__ pseudo,
                                 const float* __restrict__ mu,
                                 const float* __restrict__ sigma,
                                 float* __restrict__ acc) {
    const int f = threadIdx.x & 31;
    const float m0 = mu[f * 3 + 0], m1 = mu[f * 3 + 1], m2 = mu[f * 3 + 2];
    const float s0 = sigma[f * 3 + 0], s1 = sigma[f * 3 + 1], s2 = sigma[f * 3 + 2];
    const float c0 = 0.5f / (1e-14f + s0 * s0);
    const float c1 = 0.5f / (1e-14f + s1 * s1);
    const float c2 = 0.5f / (1e-14f + s2 * s2);
    int group   = (blockIdx.x * blockDim.x + threadIdx.x) >> 5;
    int ngroups = (gridDim.x * blockDim.x) >> 5;
    for (int e = group; e < E_EDGES; e += ngroups) {
        const int row = edge_index[e];
        const int col = edge_index[E_EDGES + e];
        const float p0 = pseudo[e * 3 + 0], p1 = pseudo[e * 3 + 1], p2 = pseudo[e * 3 + 2];
        const float d0 = p0 - m0, d1 = p1 - m1, d2 = p2 - m2;
        const float g  = __expf(-(c0 * d0 * d0 + c1 * d1 * d1 + c2 * d2 * d2));
        atomicAdd(&acc[(size_t)row * F_DIM + f], x[(size_t)col * F_DIM + f] * g);
    }
}

__global__ void gmm_linear2(const float* __restrict__ acc,
                            const float* __restrict__ W,
                            const float* __restrict__ b,
                            float* __restrict__ out) {
    const int o = threadIdx.x & 31;
    const int n = (blockIdx.x * blockDim.x + threadIdx.x) >> 5;
    if (n >= N_NODES) return;
    const float* wrow = W + (size_t)o * F_DIM;
    const float* ap   = acc + (size_t)n * F_DIM;
    float s = b[o];
#pragma unroll
    for (int t = 0; t < 8; ++t) {
        const float4 wv = ((const float4*)wrow)[t];
        const float4 av = ((const float4*)ap)[t];
        s += av.x * wv.x + av.y * wv.y + av.z * wv.z + av.w * wv.w;
    }
    out[(size_t)n * F_DIM + o] = s;
}

extern "C" void kernel_launch(void* const* d_in, const int* in_sizes, int n_in,
                              void* d_out, int out_size, void* d_ws, size_t ws_size,
                              hipStream_t stream) {
    const float* x          = (const float*)d_in[0];
    const int*   edge_index = (const int*)  d_in[1];
    const float* pseudo     = (const float*)d_in[2];
    const float* mu         = (const float*)d_in[3];
    const float* sigma      = (const float*)d_in[4];
    const float* W          = (const float*)d_in[5];
    const float* b          = (const float*)d_in[6];
    float*       out        = (float*)d_out;

    // Workspace layout (round-6 sizes: ~30.2 MB)
    const size_t CNT_OFF    = 0;                                  // N ints
    const size_t SPC_OFF    = (size_t)N_NODES * 4;                // 1 int
    const size_t ZERO_BYTES = SPC_OFF + 4;                        // memset range
    const size_t REC_OFF    = 409600;                             // 4K-aligned
    const size_t REC_BYTES  = (size_t)N_NODES * CAP * 8;          // 25.6 MB
    const size_t SPILL_OFF  = REC_OFF + REC_BYTES;
    const size_t NEED       = SPILL_OFF + (size_t)SPILL_MAX * sizeof(Spill);

    if (ws_size >= NEED) {
        char* ws = (char*)d_ws;
        int*                cnt      = (int*)(ws + CNT_OFF);
        int*                spillcnt = (int*)(ws + SPC_OFF);
        unsigned long long* rec      = (unsigned long long*)(ws + REC_OFF);
        Spill*              spill    = (Spill*)(ws + SPILL_OFF);

        hipMemsetAsync(ws, 0, ZERO_BYTES, stream);    // cnt + spillcnt only
        k_bucket<<<8 * NSTRIPES, 256, 0, stream>>>(
            edge_index, pseudo, cnt, spillcnt, rec, spill);
        // 25000 blocks x 4 waves = 100000 nodes exactly
        k_gather_linear<<<N_NODES / 4, 256, 0, stream>>>(
            x, cnt, rec, spillcnt, spill, mu, sigma, W, b, out);
    } else {
        float* acc = (float*)d_ws;
        hipMemsetAsync(acc, 0, (size_t)N_NODES * F_DIM * sizeof(float), stream);
        gmm_edge_scatter<<<4096, 256, 0, stream>>>(x, edge_index, pseudo, mu, sigma, acc);
        gmm_linear2<<<(N_NODES * 32 + 255) / 256, 256, 0, stream>>>(acc, W, b, out);
    }
}